// Round 2
// baseline (3217.924 us; speedup 1.0000x reference)
//
#include <hip/hip_runtime.h>
#include <hip/hip_bf16.h>

#define N_IN      256
#define N_OUTC    128
#define BIN_ROWS  64
#define RCAP_MAX  1152
#define SPILL_CAP 4096

typedef __attribute__((ext_vector_type(8))) short bf16x8;
typedef __attribute__((ext_vector_type(4))) float f32x4;
typedef unsigned short ushort_t;
typedef unsigned int uint_t;

__device__ inline unsigned short f2bf(float f) {
    unsigned u = __float_as_uint(f);
    unsigned r = u + 0x7fffu + ((u >> 16) & 1u);
    return (unsigned short)(r >> 16);
}
__device__ inline float bf_lo(uint_t g) { return __uint_as_float(g << 16); }
__device__ inline float bf_hi(uint_t g) { return __uint_as_float(g & 0xFFFF0000u); }

// ---------------- W fp32 [128,256] -> bf16 ----------------
__global__ void cvtW_kernel(const float* __restrict__ W, ushort_t* __restrict__ wb, int n) {
    int i = blockIdx.x * blockDim.x + threadIdx.x;
    if (i < n) wb[i] = f2bf(W[i]);
}

// ---------------- h = x @ W^T + b  (output bf16) ----------------
// block = 256 (4 waves); wave: 16 rows x 32 cols (2 MFMA 16x16x32); block: 16 rows x 128 cols.
__global__ __launch_bounds__(256) void gemm_h_kernel(const float* __restrict__ x,
                                                     const ushort_t* __restrict__ wb,
                                                     const float* __restrict__ b,
                                                     ushort_t* __restrict__ h16, int M) {
    const int wave = threadIdx.x >> 6;
    const int lane = threadIdx.x & 63;
    const int quad = lane >> 4;
    const int l16  = lane & 15;
    const int m0   = blockIdx.x * 16;
    const int colbase = wave * 32;

    f32x4 acc0 = {0.f, 0.f, 0.f, 0.f};
    f32x4 acc1 = {0.f, 0.f, 0.f, 0.f};

    const float* xrow = x + (size_t)(m0 + l16) * N_IN + quad * 8;   // A: m=lane&15, k=quad*8+j
    const ushort_t* w0 = wb + (size_t)(colbase + l16) * N_IN + quad * 8;
    const ushort_t* w1 = w0 + 16 * N_IN;

    #pragma unroll
    for (int kb = 0; kb < N_IN; kb += 32) {
        float4 a0 = *(const float4*)(xrow + kb);
        float4 a1 = *(const float4*)(xrow + kb + 4);
        union { bf16x8 v; __hip_bfloat162 h2[4]; } u;
        u.h2[0] = __float22bfloat162_rn(make_float2(a0.x, a0.y));
        u.h2[1] = __float22bfloat162_rn(make_float2(a0.z, a0.w));
        u.h2[2] = __float22bfloat162_rn(make_float2(a1.x, a1.y));
        u.h2[3] = __float22bfloat162_rn(make_float2(a1.z, a1.w));
        bf16x8 bf0 = *(const bf16x8*)(w0 + kb);
        bf16x8 bf1 = *(const bf16x8*)(w1 + kb);
        acc0 = __builtin_amdgcn_mfma_f32_16x16x32_bf16(u.v, bf0, acc0, 0, 0, 0);
        acc1 = __builtin_amdgcn_mfma_f32_16x16x32_bf16(u.v, bf1, acc1, 0, 0, 0);
    }

    // C/D: row = quad*4 + reg, col = lane&15
    const int c0 = colbase + l16;
    const int c1 = c0 + 16;
    const float bv0 = b[c0];
    const float bv1 = b[c1];
    ushort_t* hp = h16 + (size_t)(m0 + quad * 4) * N_OUTC;
    #pragma unroll
    for (int r = 0; r < 4; r++) {
        hp[(size_t)r * N_OUTC + c0] = f2bf(acc0[r] + bv0);
        hp[(size_t)r * N_OUTC + c1] = f2bf(acc1[r] + bv1);
    }
}

// ---------------- pass 1: coarse bin (64 rows/bin) x XCD scatter ----------------
// entry: .x = col | (rowlo<<17), .y = val bits
__global__ void bin_kernel(const int* __restrict__ rows, const int* __restrict__ cols,
                           const float* __restrict__ vals, int E,
                           int* __restrict__ counts, int2* __restrict__ regions, int rcap,
                           int* __restrict__ spillCnt, int4* __restrict__ spill) {
    int e = blockIdx.x * blockDim.x + threadIdx.x;
    if (e >= E) return;
    // HW_REG_XCC_ID (id=20, offset 0, width 4): imm = 20 | (0<<6) | ((4-1)<<11) = 6164.
    // Mask &7 keeps this correctness-safe even if the id is wrong (locality hint only).
    int xcc = __builtin_amdgcn_s_getreg(6164) & 7;
    int r = rows[e], c = cols[e];
    float v = vals[e];
    int reg = ((r >> 6) << 3) + xcc;
    int pos = atomicAdd(&counts[reg], 1);
    if (pos < rcap) {
        regions[(size_t)reg * rcap + pos] = make_int2(c | ((r & 63) << 17), __float_as_int(v));
    } else {
        int sp = atomicAdd(spillCnt, 1);
        if (sp < SPILL_CAP) spill[sp] = make_int4(r, c, __float_as_int(v), 0);
    }
}

// ---------------- pass 2: per-bin LDS accumulate + concat epilogue ----------------
// LDS acc layout permuted: col c at [(c&1)*64 + (c>>1)] -> lane l owns cols 2l,2l+1 at
// [l] and [64+l] -> ds_add banks l%32 (2-way, free).
__global__ __launch_bounds__(256) void spmm_bin_kernel(const ushort_t* __restrict__ h16,
                                                       const int* __restrict__ counts,
                                                       const int2* __restrict__ regions, int rcap,
                                                       const int* __restrict__ prev,
                                                       float* __restrict__ out, int Ndst) {
    __shared__ float acc[BIN_ROWS * 128];
    const int bin  = blockIdx.x;
    const int tid  = threadIdx.x;
    const int wave = tid >> 6;
    const int lane = tid & 63;

    #pragma unroll
    for (int i = tid; i < BIN_ROWS * 128; i += 256) acc[i] = 0.f;
    __syncthreads();

    for (int xr = 0; xr < 8; ++xr) {
        const int reg = bin * 8 + xr;
        int cnt = counts[reg];
        if (cnt > rcap) cnt = rcap;
        const int2* ep = regions + (size_t)reg * rcap;
        for (int base = wave * 4; base < cnt; base += 16) {
            int n = cnt - base; if (n > 4) n = 4;
            int2 e0, e1, e2, e3;
            e0 = ep[base];
            if (n > 1) e1 = ep[base + 1];
            if (n > 2) e2 = ep[base + 2];
            if (n > 3) e3 = ep[base + 3];
            uint_t p0 = (uint_t)e0.x;
            uint_t g0 = *(const uint_t*)(h16 + (size_t)(p0 & 0x1FFFFu) * N_OUTC + 2 * lane);
            uint_t p1 = 0, g1 = 0, p2 = 0, g2 = 0, p3 = 0, g3 = 0;
            if (n > 1) { p1 = (uint_t)e1.x; g1 = *(const uint_t*)(h16 + (size_t)(p1 & 0x1FFFFu) * N_OUTC + 2 * lane); }
            if (n > 2) { p2 = (uint_t)e2.x; g2 = *(const uint_t*)(h16 + (size_t)(p2 & 0x1FFFFu) * N_OUTC + 2 * lane); }
            if (n > 3) { p3 = (uint_t)e3.x; g3 = *(const uint_t*)(h16 + (size_t)(p3 & 0x1FFFFu) * N_OUTC + 2 * lane); }
            {
                float v = __int_as_float(e0.y); int rl = (int)(p0 >> 17);
                atomicAdd(&acc[rl * 128 + lane],      v * bf_lo(g0));
                atomicAdd(&acc[rl * 128 + 64 + lane], v * bf_hi(g0));
            }
            if (n > 1) {
                float v = __int_as_float(e1.y); int rl = (int)(p1 >> 17);
                atomicAdd(&acc[rl * 128 + lane],      v * bf_lo(g1));
                atomicAdd(&acc[rl * 128 + 64 + lane], v * bf_hi(g1));
            }
            if (n > 2) {
                float v = __int_as_float(e2.y); int rl = (int)(p2 >> 17);
                atomicAdd(&acc[rl * 128 + lane],      v * bf_lo(g2));
                atomicAdd(&acc[rl * 128 + 64 + lane], v * bf_hi(g2));
            }
            if (n > 3) {
                float v = __int_as_float(e3.y); int rl = (int)(p3 >> 17);
                atomicAdd(&acc[rl * 128 + lane],      v * bf_lo(g3));
                atomicAdd(&acc[rl * 128 + 64 + lane], v * bf_hi(g3));
            }
        }
    }
    __syncthreads();

    // epilogue: out[r][0:128) = h[prev[r]], out[r][128:256) = acc (un-permute)
    const int r0 = bin * BIN_ROWS;
    for (int rr = wave; rr < BIN_ROWS; rr += 4) {
        int r = r0 + rr;
        if (r >= Ndst) break;
        int p = prev[r];
        uint_t g = *(const uint_t*)(h16 + (size_t)p * N_OUTC + 2 * lane);
        float2* o = (float2*)(out + (size_t)r * 256);
        o[lane]      = make_float2(bf_lo(g), bf_hi(g));
        o[64 + lane] = make_float2(acc[rr * 128 + lane], acc[rr * 128 + 64 + lane]);
    }
}

// ---------------- spill fixup (expected empty) ----------------
__global__ void spill_kernel(const ushort_t* __restrict__ h16, const int4* __restrict__ spill,
                             const int* __restrict__ spillCnt, float* __restrict__ out) {
    int t = blockIdx.x * blockDim.x + threadIdx.x;
    int idx = t >> 6, lane = t & 63;
    int n = *spillCnt; if (n > SPILL_CAP) n = SPILL_CAP;
    if (idx >= n) return;
    int4 s = spill[idx];
    uint_t g = *(const uint_t*)(h16 + (size_t)s.y * N_OUTC + 2 * lane);
    float v = __int_as_float(s.z);
    atomicAdd(&out[(size_t)s.x * 256 + 128 + 2 * lane],     v * bf_lo(g));
    atomicAdd(&out[(size_t)s.x * 256 + 128 + 2 * lane + 1], v * bf_hi(g));
}

// ---------------- fallback path (ws too small; not expected) ----------------
__global__ void concat_only_kernel(const ushort_t* __restrict__ h16, const int* __restrict__ prev,
                                   float* __restrict__ out, int Ndst) {
    int t = blockIdx.x * blockDim.x + threadIdx.x;
    int r = t >> 6, lane = t & 63;
    if (r >= Ndst) return;
    uint_t g = *(const uint_t*)(h16 + (size_t)prev[r] * N_OUTC + 2 * lane);
    ((float2*)out)[(size_t)r * 128 + lane] = make_float2(bf_lo(g), bf_hi(g));
}

__global__ void spmm_atomic_kernel(const ushort_t* __restrict__ h16, const int* __restrict__ rows,
                                   const int* __restrict__ cols, const float* __restrict__ vals,
                                   int E, float* __restrict__ out) {
    long long t = (long long)blockIdx.x * blockDim.x + threadIdx.x;
    int e = (int)(t >> 6), lane = (int)(t & 63);
    if (e >= E) return;
    uint_t g = *(const uint_t*)(h16 + (size_t)cols[e] * N_OUTC + 2 * lane);
    float v = vals[e];
    int r = rows[e];
    atomicAdd(&out[(size_t)r * 256 + 128 + 2 * lane],     v * bf_lo(g));
    atomicAdd(&out[(size_t)r * 256 + 128 + 2 * lane + 1], v * bf_hi(g));
}

extern "C" void kernel_launch(void* const* d_in, const int* in_sizes, int n_in,
                              void* d_out, int out_size, void* d_ws, size_t ws_size,
                              hipStream_t stream) {
    const float* x    = (const float*)d_in[0];
    const float* W    = (const float*)d_in[1];
    const float* b    = (const float*)d_in[2];
    const float* vals = (const float*)d_in[3];
    const int*   rows = (const int*)d_in[4];
    const int*   cols = (const int*)d_in[5];
    const int*   prev = (const int*)d_in[6];
    float* out = (float*)d_out;

    const int Nsrc = in_sizes[0] / N_IN;   // 100000
    const int E    = in_sizes[3];          // 3200000
    const int Ndst = in_sizes[6];          // 50000
    const int NB   = (Ndst + BIN_ROWS - 1) / BIN_ROWS;   // 782
    const int NB8  = NB * 8;

    char* ws = (char*)d_ws;
    size_t off = 0;
    ushort_t* h16 = (ushort_t*)(ws + off);
    off += (size_t)Nsrc * N_OUTC * sizeof(ushort_t);               // 25.6 MB
    ushort_t* wb = (ushort_t*)(ws + off);
    off += (size_t)N_OUTC * N_IN * sizeof(ushort_t);               // 64 KB
    off = (off + 255) & ~(size_t)255;
    int* counts = (int*)(ws + off);                                 // NB8 ints + spillCnt
    int* spillCnt = counts + NB8;
    size_t memsetBytes = (size_t)NB8 * 4 + 4;
    off += memsetBytes;
    off = (off + 255) & ~(size_t)255;
    int4* spill = (int4*)(ws + off);
    off += (size_t)SPILL_CAP * sizeof(int4);
    off = (off + 255) & ~(size_t)255;
    size_t regOff = off;

    int rcap = 0;
    if (ws_size > regOff) {
        size_t per = (size_t)NB8 * sizeof(int2);
        long long maxcap = (long long)((ws_size - regOff) / per);
        rcap = (int)(maxcap < RCAP_MAX ? maxcap : RCAP_MAX);
    }

    cvtW_kernel<<<(N_OUTC * N_IN + 255) / 256, 256, 0, stream>>>(W, wb, N_OUTC * N_IN);
    gemm_h_kernel<<<Nsrc / 16, 256, 0, stream>>>(x, wb, b, h16, Nsrc);

    if (rcap >= 384) {
        int2* regions = (int2*)(ws + regOff);
        hipMemsetAsync(counts, 0, memsetBytes, stream);
        bin_kernel<<<(E + 255) / 256, 256, 0, stream>>>(rows, cols, vals, E,
                                                        counts, regions, rcap, spillCnt, spill);
        spmm_bin_kernel<<<NB, 256, 0, stream>>>(h16, counts, regions, rcap, prev, out, Ndst);
        spill_kernel<<<(SPILL_CAP * 64) / 256, 256, 0, stream>>>(h16, spill, spillCnt, out);
    } else {
        hipMemsetAsync(out, 0, (size_t)out_size * sizeof(float), stream);
        concat_only_kernel<<<((size_t)Ndst * 64 + 255) / 256, 256, 0, stream>>>(h16, prev, out, Ndst);
        spmm_atomic_kernel<<<((size_t)E * 64 + 255) / 256, 256, 0, stream>>>(h16, rows, cols, vals, E, out);
    }
}

// Round 3
// 742.926 us; speedup vs baseline: 4.3314x; 4.3314x over previous
//
#include <hip/hip_runtime.h>
#include <hip/hip_bf16.h>

#define N_IN      256
#define N_OUTC    128
#define BIN_ROWS  64
#define CAP_MAX   192
#define CAP_MIN   128
#define RCAP_MAX  768
#define RCAP_MIN  640
#define SPILL_CAP 8192

typedef __attribute__((ext_vector_type(8))) short bf16x8;
typedef __attribute__((ext_vector_type(4))) float f32x4;
typedef unsigned short ushort_t;
typedef unsigned int uint_t;

__device__ inline unsigned short f2bf(float f) {
    unsigned u = __float_as_uint(f);
    unsigned r = u + 0x7fffu + ((u >> 16) & 1u);
    return (unsigned short)(r >> 16);
}
__device__ inline float bf_lo(uint_t g) { return __uint_as_float(g << 16); }
__device__ inline float bf_hi(uint_t g) { return __uint_as_float(g & 0xFFFF0000u); }

// ---------------- W fp32 [128,256] -> bf16 ----------------
__global__ void cvtW_kernel(const float* __restrict__ W, ushort_t* __restrict__ wb, int n) {
    int i = blockIdx.x * blockDim.x + threadIdx.x;
    if (i < n) wb[i] = f2bf(W[i]);
}

// ---------------- h = x @ W^T + b  (output bf16) ----------------
__global__ __launch_bounds__(256) void gemm_h_kernel(const float* __restrict__ x,
                                                     const ushort_t* __restrict__ wb,
                                                     const float* __restrict__ b,
                                                     ushort_t* __restrict__ h16, int M) {
    const int wave = threadIdx.x >> 6;
    const int lane = threadIdx.x & 63;
    const int quad = lane >> 4;
    const int l16  = lane & 15;
    const int m0   = blockIdx.x * 16;
    const int colbase = wave * 32;

    f32x4 acc0 = {0.f, 0.f, 0.f, 0.f};
    f32x4 acc1 = {0.f, 0.f, 0.f, 0.f};

    const float* xrow = x + (size_t)(m0 + l16) * N_IN + quad * 8;   // A: m=lane&15, k=quad*8+j
    const ushort_t* w0 = wb + (size_t)(colbase + l16) * N_IN + quad * 8;
    const ushort_t* w1 = w0 + 16 * N_IN;

    #pragma unroll
    for (int kb = 0; kb < N_IN; kb += 32) {
        float4 a0 = *(const float4*)(xrow + kb);
        float4 a1 = *(const float4*)(xrow + kb + 4);
        union { bf16x8 v; __hip_bfloat162 h2[4]; } u;
        u.h2[0] = __float22bfloat162_rn(make_float2(a0.x, a0.y));
        u.h2[1] = __float22bfloat162_rn(make_float2(a0.z, a0.w));
        u.h2[2] = __float22bfloat162_rn(make_float2(a1.x, a1.y));
        u.h2[3] = __float22bfloat162_rn(make_float2(a1.z, a1.w));
        bf16x8 bf0 = *(const bf16x8*)(w0 + kb);
        bf16x8 bf1 = *(const bf16x8*)(w1 + kb);
        acc0 = __builtin_amdgcn_mfma_f32_16x16x32_bf16(u.v, bf0, acc0, 0, 0, 0);
        acc1 = __builtin_amdgcn_mfma_f32_16x16x32_bf16(u.v, bf1, acc1, 0, 0, 0);
    }

    // C/D: row = quad*4 + reg, col = lane&15
    const int c0 = colbase + l16;
    const int c1 = c0 + 16;
    const float bv0 = b[c0];
    const float bv1 = b[c1];
    ushort_t* hp = h16 + (size_t)(m0 + quad * 4) * N_OUTC;
    #pragma unroll
    for (int r = 0; r < 4; r++) {
        hp[(size_t)r * N_OUTC + c0] = f2bf(acc0[r] + bv0);
        hp[(size_t)r * N_OUTC + c1] = f2bf(acc1[r] + bv1);
    }
}

// ---------------- stage 1: XCD-local coarse bin scatter ----------------
// region = (row>>6)*8 + xcd. Only one XCD writes a given region -> its L2 merges
// the tail line into full-line evictions. entry .x = col | (rowlo<<17), .y = val bits.
__global__ void bin_kernel(const int* __restrict__ rows, const int* __restrict__ cols,
                           const float* __restrict__ vals, int E,
                           int* __restrict__ regCounts, int2* __restrict__ regions, int rcap,
                           int* __restrict__ spillCnt, int4* __restrict__ spill) {
    int e = blockIdx.x * blockDim.x + threadIdx.x;
    if (e >= E) return;
    // HW_REG_XCC_ID (id=20, offset 0, width 4). &7 keeps it correctness-safe (hint only).
    int xcc = __builtin_amdgcn_s_getreg(6164) & 7;
    int r = rows[e], c = cols[e];
    float v = vals[e];
    int reg = ((r >> 6) << 3) + xcc;
    int pos = atomicAdd(&regCounts[reg], 1);
    if (pos < rcap) {
        regions[(size_t)reg * rcap + pos] = make_int2(c | ((r & 63) << 17), __float_as_int(v));
    } else {
        int sp = atomicAdd(spillCnt, 1);
        if (sp < SPILL_CAP) spill[sp] = make_int4(r, c, __float_as_int(v), 0);
    }
}

// ---------------- stage 2: region -> per-row buckets (writes stay in one bin's span) ----
__global__ __launch_bounds__(256) void scatter_kernel(const int* __restrict__ regCounts,
                                                      const int2* __restrict__ regions, int rcap,
                                                      int* __restrict__ counts,
                                                      int2* __restrict__ bucket, int cap,
                                                      int* __restrict__ spillCnt, int4* __restrict__ spill) {
    const int reg = blockIdx.x;
    const int bin = reg >> 3;
    int cnt = regCounts[reg];
    if (cnt > rcap) cnt = rcap;
    const int2* ep = regions + (size_t)reg * rcap;
    for (int i = threadIdx.x; i < cnt; i += 256) {
        int2 ent = ep[i];
        int c = ent.x & 0x1FFFF;
        int r = bin * BIN_ROWS + ((uint_t)ent.x >> 17);
        int pos = atomicAdd(&counts[r], 1);
        if (pos < cap) {
            bucket[(size_t)r * cap + pos] = make_int2(c, ent.y);
        } else {
            int sp = atomicAdd(spillCnt, 1);
            if (sp < SPILL_CAP) spill[sp] = make_int4(r, c, ent.y, 0);
        }
    }
}

// ---------------- one-stage fallback build (if ws too small for regions) ----------------
__global__ void build_direct_kernel(const int* __restrict__ rows, const int* __restrict__ cols,
                                    const float* __restrict__ vals, int E,
                                    int* __restrict__ counts, int2* __restrict__ bucket, int cap,
                                    int* __restrict__ spillCnt, int4* __restrict__ spill) {
    int e = blockIdx.x * blockDim.x + threadIdx.x;
    if (e >= E) return;
    int r = rows[e];
    int pos = atomicAdd(&counts[r], 1);
    if (pos < cap) {
        bucket[(size_t)r * cap + pos] = make_int2(cols[e], __float_as_int(vals[e]));
    } else {
        int sp = atomicAdd(spillCnt, 1);
        if (sp < SPILL_CAP) spill[sp] = make_int4(r, cols[e], __float_as_int(vals[e]), 0);
    }
}

// ---------------- SpMM: wave per dst row, 8-deep MLP, bf16 gathers + concat ----------------
__global__ __launch_bounds__(256) void spmm_concat_kernel(const ushort_t* __restrict__ h16,
                                                          const int* __restrict__ counts,
                                                          const int2* __restrict__ bucket, int cap,
                                                          const int* __restrict__ prev,
                                                          float* __restrict__ out, int Ndst) {
    int r = blockIdx.x * 4 + (threadIdx.x >> 6);
    if (r >= Ndst) return;
    const int lane = threadIdx.x & 63;
    int cnt = counts[r];
    if (cnt > cap) cnt = cap;
    const int2* bk = bucket + (size_t)r * cap;

    float2 acc = {0.f, 0.f};
    int e = 0;
    for (; e + 8 <= cnt; e += 8) {
        int2 c0 = bk[e], c1 = bk[e+1], c2 = bk[e+2], c3 = bk[e+3];
        int2 c4 = bk[e+4], c5 = bk[e+5], c6 = bk[e+6], c7 = bk[e+7];
        uint_t g0 = *(const uint_t*)(h16 + (size_t)c0.x * N_OUTC + 2 * lane);
        uint_t g1 = *(const uint_t*)(h16 + (size_t)c1.x * N_OUTC + 2 * lane);
        uint_t g2 = *(const uint_t*)(h16 + (size_t)c2.x * N_OUTC + 2 * lane);
        uint_t g3 = *(const uint_t*)(h16 + (size_t)c3.x * N_OUTC + 2 * lane);
        uint_t g4 = *(const uint_t*)(h16 + (size_t)c4.x * N_OUTC + 2 * lane);
        uint_t g5 = *(const uint_t*)(h16 + (size_t)c5.x * N_OUTC + 2 * lane);
        uint_t g6 = *(const uint_t*)(h16 + (size_t)c6.x * N_OUTC + 2 * lane);
        uint_t g7 = *(const uint_t*)(h16 + (size_t)c7.x * N_OUTC + 2 * lane);
        float v0 = __int_as_float(c0.y), v1 = __int_as_float(c1.y);
        float v2 = __int_as_float(c2.y), v3 = __int_as_float(c3.y);
        float v4 = __int_as_float(c4.y), v5 = __int_as_float(c5.y);
        float v6 = __int_as_float(c6.y), v7 = __int_as_float(c7.y);
        acc.x += v0 * bf_lo(g0); acc.y += v0 * bf_hi(g0);
        acc.x += v1 * bf_lo(g1); acc.y += v1 * bf_hi(g1);
        acc.x += v2 * bf_lo(g2); acc.y += v2 * bf_hi(g2);
        acc.x += v3 * bf_lo(g3); acc.y += v3 * bf_hi(g3);
        acc.x += v4 * bf_lo(g4); acc.y += v4 * bf_hi(g4);
        acc.x += v5 * bf_lo(g5); acc.y += v5 * bf_hi(g5);
        acc.x += v6 * bf_lo(g6); acc.y += v6 * bf_hi(g6);
        acc.x += v7 * bf_lo(g7); acc.y += v7 * bf_hi(g7);
    }
    for (; e < cnt; e++) {
        int2 cv = bk[e];
        uint_t g = *(const uint_t*)(h16 + (size_t)cv.x * N_OUTC + 2 * lane);
        float v = __int_as_float(cv.y);
        acc.x += v * bf_lo(g); acc.y += v * bf_hi(g);
    }

    int p = prev[r];
    uint_t g = *(const uint_t*)(h16 + (size_t)p * N_OUTC + 2 * lane);
    float2* o = (float2*)(out + (size_t)r * 256);
    o[lane]      = make_float2(bf_lo(g), bf_hi(g));   // cols [0,128): 2l, 2l+1
    o[64 + lane] = make_float2(acc.x, acc.y);         // cols [128,256)
}

// ---------------- spill fixup (expected empty) ----------------
__global__ void spill_kernel(const ushort_t* __restrict__ h16, const int4* __restrict__ spill,
                             const int* __restrict__ spillCnt, float* __restrict__ out) {
    int n = *spillCnt; if (n > SPILL_CAP) n = SPILL_CAP;
    int total = n * 64;
    for (int t = blockIdx.x * blockDim.x + threadIdx.x; t < total; t += gridDim.x * blockDim.x) {
        int idx = t >> 6, lane = t & 63;
        int4 s = spill[idx];
        uint_t g = *(const uint_t*)(h16 + (size_t)s.y * N_OUTC + 2 * lane);
        float v = __int_as_float(s.z);
        atomicAdd(&out[(size_t)s.x * 256 + 128 + 2 * lane],     v * bf_lo(g));
        atomicAdd(&out[(size_t)s.x * 256 + 128 + 2 * lane + 1], v * bf_hi(g));
    }
}

// ---------------- last-resort fallback (tiny ws) ----------------
__global__ void concat_only_kernel(const ushort_t* __restrict__ h16, const int* __restrict__ prev,
                                   float* __restrict__ out, int Ndst) {
    int t = blockIdx.x * blockDim.x + threadIdx.x;
    int r = t >> 6, lane = t & 63;
    if (r >= Ndst) return;
    uint_t g = *(const uint_t*)(h16 + (size_t)prev[r] * N_OUTC + 2 * lane);
    ((float2*)out)[(size_t)r * 128 + lane] = make_float2(bf_lo(g), bf_hi(g));
}

__global__ void spmm_atomic_kernel(const ushort_t* __restrict__ h16, const int* __restrict__ rows,
                                   const int* __restrict__ cols, const float* __restrict__ vals,
                                   int E, float* __restrict__ out) {
    long long t = (long long)blockIdx.x * blockDim.x + threadIdx.x;
    int e = (int)(t >> 6), lane = (int)(t & 63);
    if (e >= E) return;
    uint_t g = *(const uint_t*)(h16 + (size_t)cols[e] * N_OUTC + 2 * lane);
    float v = vals[e];
    int r = rows[e];
    atomicAdd(&out[(size_t)r * 256 + 128 + 2 * lane],     v * bf_lo(g));
    atomicAdd(&out[(size_t)r * 256 + 128 + 2 * lane + 1], v * bf_hi(g));
}

extern "C" void kernel_launch(void* const* d_in, const int* in_sizes, int n_in,
                              void* d_out, int out_size, void* d_ws, size_t ws_size,
                              hipStream_t stream) {
    const float* x    = (const float*)d_in[0];
    const float* W    = (const float*)d_in[1];
    const float* b    = (const float*)d_in[2];
    const float* vals = (const float*)d_in[3];
    const int*   rows = (const int*)d_in[4];
    const int*   cols = (const int*)d_in[5];
    const int*   prev = (const int*)d_in[6];
    float* out = (float*)d_out;

    const int Nsrc = in_sizes[0] / N_IN;   // 100000
    const int E    = in_sizes[3];          // 3200000
    const int Ndst = in_sizes[6];          // 50000
    const int NB   = (Ndst + BIN_ROWS - 1) / BIN_ROWS;   // 782
    const int NB8  = NB * 8;

    char* ws = (char*)d_ws;
    size_t off = 0;
    ushort_t* h16 = (ushort_t*)(ws + off);
    off += (size_t)Nsrc * N_OUTC * sizeof(ushort_t);               // 25.6 MB
    ushort_t* wb = (ushort_t*)(ws + off);
    off += (size_t)N_OUTC * N_IN * sizeof(ushort_t);               // 64 KB
    off = (off + 255) & ~(size_t)255;
    // meta zone (single memset): regCounts[NB8] + counts[Ndst] + spillCnt[1]
    int* regCounts = (int*)(ws + off);
    int* counts    = regCounts + NB8;
    int* spillCnt  = counts + Ndst;
    size_t metaBytes = ((size_t)NB8 + Ndst + 1) * sizeof(int);
    off += metaBytes;
    off = (off + 255) & ~(size_t)255;
    int4* spill = (int4*)(ws + off);
    off += (size_t)SPILL_CAP * sizeof(int4);
    off = (off + 255) & ~(size_t)255;
    size_t bucketOff = off;

    // bucket capacity
    int cap = 0;
    size_t bucketPer = (size_t)Ndst * sizeof(int2);
    if (ws_size > bucketOff) {
        long long maxcap = (long long)((ws_size - bucketOff) / bucketPer);
        cap = (int)(maxcap < CAP_MAX ? maxcap : CAP_MAX);
    }

    cvtW_kernel<<<(N_OUTC * N_IN + 255) / 256, 256, 0, stream>>>(W, wb, N_OUTC * N_IN);
    gemm_h_kernel<<<Nsrc / 16, 256, 0, stream>>>(x, wb, b, h16, Nsrc);

    if (cap >= CAP_MIN) {
        int2* bucket = (int2*)(ws + bucketOff);
        size_t regOff = (bucketOff + (size_t)cap * bucketPer + 255) & ~(size_t)255;
        int rcap = 0;
        if (ws_size > regOff) {
            size_t per = (size_t)NB8 * sizeof(int2);
            long long maxr = (long long)((ws_size - regOff) / per);
            rcap = (int)(maxr < RCAP_MAX ? maxr : RCAP_MAX);
        }
        hipMemsetAsync(regCounts, 0, metaBytes, stream);
        if (rcap >= RCAP_MIN) {
            int2* regions = (int2*)(ws + regOff);
            bin_kernel<<<(E + 255) / 256, 256, 0, stream>>>(rows, cols, vals, E,
                                                            regCounts, regions, rcap, spillCnt, spill);
            scatter_kernel<<<NB8, 256, 0, stream>>>(regCounts, regions, rcap,
                                                    counts, bucket, cap, spillCnt, spill);
        } else {
            build_direct_kernel<<<(E + 255) / 256, 256, 0, stream>>>(rows, cols, vals, E,
                                                                     counts, bucket, cap, spillCnt, spill);
        }
        spmm_concat_kernel<<<(Ndst + 3) / 4, 256, 0, stream>>>(h16, counts, bucket, cap, prev, out, Ndst);
        spill_kernel<<<64, 256, 0, stream>>>(h16, spill, spillCnt, out);
    } else {
        hipMemsetAsync(out, 0, (size_t)out_size * sizeof(float), stream);
        concat_only_kernel<<<((size_t)Ndst * 64 + 255) / 256, 256, 0, stream>>>(h16, prev, out, Ndst);
        spmm_atomic_kernel<<<((size_t)E * 64 + 255) / 256, 256, 0, stream>>>(h16, rows, cols, vals, E, out);
    }
}

// Round 4
// 486.793 us; speedup vs baseline: 6.6105x; 1.5262x over previous
//
#include <hip/hip_runtime.h>
#include <hip/hip_bf16.h>

#define N_IN      256
#define N_OUTC    128
#define RPS       512      // rows per superbin
#define RPS_SHIFT 9
#define TILE      4096     // edges per buildA block
#define EPT       16       // edges per thread in buildA
#define SPILL_CAP 8192

typedef __attribute__((ext_vector_type(8))) short bf16x8;
typedef __attribute__((ext_vector_type(4))) float f32x4;
typedef unsigned short ushort_t;
typedef unsigned int uint_t;

__device__ inline unsigned short f2bf(float f) {
    unsigned u = __float_as_uint(f);
    unsigned r = u + 0x7fffu + ((u >> 16) & 1u);
    return (unsigned short)(r >> 16);
}
__device__ inline float bf_lo(uint_t g) { return __uint_as_float(g << 16); }
__device__ inline float bf_hi(uint_t g) { return __uint_as_float(g & 0xFFFF0000u); }

// ---------------- W fp32 [128,256] -> bf16 ----------------
__global__ void cvtW_kernel(const float* __restrict__ W, ushort_t* __restrict__ wb, int n) {
    int i = blockIdx.x * blockDim.x + threadIdx.x;
    if (i < n) wb[i] = f2bf(W[i]);
}

// ---------------- h = x @ W^T + b  (output bf16) ----------------
__global__ __launch_bounds__(256) void gemm_h_kernel(const float* __restrict__ x,
                                                     const ushort_t* __restrict__ wb,
                                                     const float* __restrict__ b,
                                                     ushort_t* __restrict__ h16, int M) {
    const int wave = threadIdx.x >> 6;
    const int lane = threadIdx.x & 63;
    const int quad = lane >> 4;
    const int l16  = lane & 15;
    const int m0   = blockIdx.x * 16;
    const int colbase = wave * 32;

    f32x4 acc0 = {0.f, 0.f, 0.f, 0.f};
    f32x4 acc1 = {0.f, 0.f, 0.f, 0.f};

    const float* xrow = x + (size_t)(m0 + l16) * N_IN + quad * 8;   // A: m=lane&15, k=quad*8+j
    const ushort_t* w0 = wb + (size_t)(colbase + l16) * N_IN + quad * 8;
    const ushort_t* w1 = w0 + 16 * N_IN;

    #pragma unroll
    for (int kb = 0; kb < N_IN; kb += 32) {
        float4 a0 = *(const float4*)(xrow + kb);
        float4 a1 = *(const float4*)(xrow + kb + 4);
        union { bf16x8 v; __hip_bfloat162 h2[4]; } u;
        u.h2[0] = __float22bfloat162_rn(make_float2(a0.x, a0.y));
        u.h2[1] = __float22bfloat162_rn(make_float2(a0.z, a0.w));
        u.h2[2] = __float22bfloat162_rn(make_float2(a1.x, a1.y));
        u.h2[3] = __float22bfloat162_rn(make_float2(a1.z, a1.w));
        bf16x8 bf0 = *(const bf16x8*)(w0 + kb);
        bf16x8 bf1 = *(const bf16x8*)(w1 + kb);
        acc0 = __builtin_amdgcn_mfma_f32_16x16x32_bf16(u.v, bf0, acc0, 0, 0, 0);
        acc1 = __builtin_amdgcn_mfma_f32_16x16x32_bf16(u.v, bf1, acc1, 0, 0, 0);
    }

    // C/D: row = quad*4 + reg, col = lane&15
    const int c0 = colbase + l16;
    const int c1 = c0 + 16;
    const float bv0 = b[c0];
    const float bv1 = b[c1];
    ushort_t* hp = h16 + (size_t)(m0 + quad * 4) * N_OUTC;
    #pragma unroll
    for (int r = 0; r < 4; r++) {
        hp[(size_t)r * N_OUTC + c0] = f2bf(acc0[r] + bv0);
        hp[(size_t)r * N_OUTC + c1] = f2bf(acc1[r] + bv1);
    }
}

// ---------------- buildA: LDS-ranked superbin binning, coalesced writes ----------------
// entry .x = col | (rowlocal<<17)  (col 17b, rowlocal 9b), .y = val fp32 bits
__global__ __launch_bounds__(256) void buildA_kernel(const int* __restrict__ rows,
                                                     const int* __restrict__ cols,
                                                     const float* __restrict__ vals, int E,
                                                     int* __restrict__ sbCount,
                                                     int2* __restrict__ sbList, int sbCap, int nsb,
                                                     int* __restrict__ spillCnt, int4* __restrict__ spill) {
    __shared__ int cur[256];     // nsb <= 256
    __shared__ int gbase[256];
    const int tid = threadIdx.x;
    const int base = blockIdx.x * TILE;

    for (int i = tid; i < nsb; i += 256) cur[i] = 0;
    __syncthreads();

    int ex[EPT]; int evb[EPT]; int esb[EPT]; int erk[EPT];
    #pragma unroll
    for (int k = 0; k < EPT; k++) {
        int e = base + tid + k * 256;
        if (e < E) {
            int r = rows[e], c = cols[e];
            evb[k] = __float_as_int(vals[e]);
            esb[k] = r >> RPS_SHIFT;
            ex[k]  = c | ((r & (RPS - 1)) << 17);
            erk[k] = atomicAdd(&cur[esb[k]], 1);
        } else esb[k] = -1;
    }
    __syncthreads();
    for (int i = tid; i < nsb; i += 256) gbase[i] = atomicAdd(&sbCount[i], cur[i]);
    __syncthreads();

    #pragma unroll
    for (int k = 0; k < EPT; k++) {
        if (esb[k] < 0) continue;
        int pos = gbase[esb[k]] + erk[k];
        if (pos < sbCap) {
            sbList[(size_t)esb[k] * sbCap + pos] = make_int2(ex[k], evb[k]);
        } else {
            int sp = atomicAdd(spillCnt, 1);
            if (sp < SPILL_CAP)
                spill[sp] = make_int4((esb[k] << RPS_SHIFT) + (int)(((uint_t)ex[k]) >> 17),
                                      ex[k] & 0x1FFFF, evb[k], 0);
        }
    }
}

// ---------------- exclusive scan of clamped superbin totals (1 block) ----------------
__global__ __launch_bounds__(256) void sbscan_kernel(const int* __restrict__ sbCount, int sbCap,
                                                     int* __restrict__ sbBase, int nsb) {
    __shared__ int a[256], bsh[256];
    int tid = threadIdx.x;
    int v = 0;
    if (tid < nsb) { v = sbCount[tid]; if (v > sbCap) v = sbCap; }
    a[tid] = v; __syncthreads();
    int* src = a; int* dst = bsh;
    for (int off = 1; off < 256; off <<= 1) {
        dst[tid] = src[tid] + ((tid >= off) ? src[tid - off] : 0);
        __syncthreads();
        int* t = src; src = dst; dst = t;
    }
    if (tid < nsb) sbBase[tid] = tid ? src[tid - 1] : 0;
}

// ---------------- sort: superbin list -> CSR (in-L2 counting sort) ----------------
__global__ __launch_bounds__(256) void sort_kernel(const int* __restrict__ sbCount,
                                                   const int* __restrict__ sbBase,
                                                   const int2* __restrict__ sbList, int sbCap,
                                                   int2* __restrict__ csr,
                                                   int* __restrict__ rowStart, int* __restrict__ rowCnt,
                                                   int Ndst) {
    __shared__ int hist[RPS];
    __shared__ int scanA[RPS];
    __shared__ int scanB[RPS];
    __shared__ int cur[RPS];
    const int sb  = blockIdx.x;
    const int tid = threadIdx.x;
    int len = sbCount[sb]; if (len > sbCap) len = sbCap;
    const int base = sbBase[sb];
    const int2* lp = sbList + (size_t)sb * sbCap;

    hist[tid] = 0; hist[tid + 256] = 0;
    __syncthreads();
    for (int i = tid; i < len; i += 256) {
        int rl = (int)(((uint_t)lp[i].x) >> 17);
        atomicAdd(&hist[rl], 1);
    }
    __syncthreads();
    scanA[tid] = hist[tid]; scanA[tid + 256] = hist[tid + 256];
    __syncthreads();
    int* src = scanA; int* dst = scanB;
    for (int off = 1; off < RPS; off <<= 1) {
        int i0 = tid, i1 = tid + 256;
        dst[i0] = src[i0] + ((i0 >= off) ? src[i0 - off] : 0);
        dst[i1] = src[i1] + ((i1 >= off) ? src[i1 - off] : 0);
        __syncthreads();
        int* t = src; src = dst; dst = t;
    }
    #pragma unroll
    for (int j = 0; j < 2; j++) {
        int i = tid + j * 256;
        int excl = i ? src[i - 1] : 0;
        cur[i] = excl;
        int r = sb * RPS + i;
        if (r < Ndst) { rowStart[r] = base + excl; rowCnt[r] = hist[i]; }
    }
    __syncthreads();
    for (int i = tid; i < len; i += 256) {
        int2 e = lp[i];
        int rl = (int)(((uint_t)e.x) >> 17);
        int pos = atomicAdd(&cur[rl], 1);
        csr[(size_t)base + pos] = make_int2(e.x & 0x1FFFF, e.y);
    }
}

// ---------------- SpMM: wave per dst row over CSR, 8-deep MLP + concat ----------------
__global__ __launch_bounds__(256) void spmm_concat_kernel(const ushort_t* __restrict__ h16,
                                                          const int* __restrict__ rowStart,
                                                          const int* __restrict__ rowCnt,
                                                          const int2* __restrict__ csr,
                                                          const int* __restrict__ prev,
                                                          float* __restrict__ out, int Ndst) {
    int r = blockIdx.x * 4 + (threadIdx.x >> 6);
    if (r >= Ndst) return;
    const int lane = threadIdx.x & 63;
    const int cnt = rowCnt[r];
    const int2* bk = csr + rowStart[r];

    float2 acc = {0.f, 0.f};
    int e = 0;
    for (; e + 8 <= cnt; e += 8) {
        int2 c0 = bk[e], c1 = bk[e+1], c2 = bk[e+2], c3 = bk[e+3];
        int2 c4 = bk[e+4], c5 = bk[e+5], c6 = bk[e+6], c7 = bk[e+7];
        uint_t g0 = *(const uint_t*)(h16 + (size_t)c0.x * N_OUTC + 2 * lane);
        uint_t g1 = *(const uint_t*)(h16 + (size_t)c1.x * N_OUTC + 2 * lane);
        uint_t g2 = *(const uint_t*)(h16 + (size_t)c2.x * N_OUTC + 2 * lane);
        uint_t g3 = *(const uint_t*)(h16 + (size_t)c3.x * N_OUTC + 2 * lane);
        uint_t g4 = *(const uint_t*)(h16 + (size_t)c4.x * N_OUTC + 2 * lane);
        uint_t g5 = *(const uint_t*)(h16 + (size_t)c5.x * N_OUTC + 2 * lane);
        uint_t g6 = *(const uint_t*)(h16 + (size_t)c6.x * N_OUTC + 2 * lane);
        uint_t g7 = *(const uint_t*)(h16 + (size_t)c7.x * N_OUTC + 2 * lane);
        float v0 = __int_as_float(c0.y), v1 = __int_as_float(c1.y);
        float v2 = __int_as_float(c2.y), v3 = __int_as_float(c3.y);
        float v4 = __int_as_float(c4.y), v5 = __int_as_float(c5.y);
        float v6 = __int_as_float(c6.y), v7 = __int_as_float(c7.y);
        acc.x += v0 * bf_lo(g0); acc.y += v0 * bf_hi(g0);
        acc.x += v1 * bf_lo(g1); acc.y += v1 * bf_hi(g1);
        acc.x += v2 * bf_lo(g2); acc.y += v2 * bf_hi(g2);
        acc.x += v3 * bf_lo(g3); acc.y += v3 * bf_hi(g3);
        acc.x += v4 * bf_lo(g4); acc.y += v4 * bf_hi(g4);
        acc.x += v5 * bf_lo(g5); acc.y += v5 * bf_hi(g5);
        acc.x += v6 * bf_lo(g6); acc.y += v6 * bf_hi(g6);
        acc.x += v7 * bf_lo(g7); acc.y += v7 * bf_hi(g7);
    }
    for (; e < cnt; e++) {
        int2 cv = bk[e];
        uint_t g = *(const uint_t*)(h16 + (size_t)cv.x * N_OUTC + 2 * lane);
        float v = __int_as_float(cv.y);
        acc.x += v * bf_lo(g); acc.y += v * bf_hi(g);
    }

    int p = prev[r];
    uint_t g = *(const uint_t*)(h16 + (size_t)p * N_OUTC + 2 * lane);
    float2* o = (float2*)(out + (size_t)r * 256);
    o[lane]      = make_float2(bf_lo(g), bf_hi(g));
    o[64 + lane] = make_float2(acc.x, acc.y);
}

// ---------------- spill fixup (expected empty) ----------------
__global__ void spill_kernel(const ushort_t* __restrict__ h16, const int4* __restrict__ spill,
                             const int* __restrict__ spillCnt, float* __restrict__ out) {
    int n = *spillCnt; if (n > SPILL_CAP) n = SPILL_CAP;
    int total = n * 64;
    for (int t = blockIdx.x * blockDim.x + threadIdx.x; t < total; t += gridDim.x * blockDim.x) {
        int idx = t >> 6, lane = t & 63;
        int4 s = spill[idx];
        uint_t g = *(const uint_t*)(h16 + (size_t)s.y * N_OUTC + 2 * lane);
        float v = __int_as_float(s.z);
        atomicAdd(&out[(size_t)s.x * 256 + 128 + 2 * lane],     v * bf_lo(g));
        atomicAdd(&out[(size_t)s.x * 256 + 128 + 2 * lane + 1], v * bf_hi(g));
    }
}

// ---------------- last-resort fallback (tiny ws) ----------------
__global__ void concat_only_kernel(const ushort_t* __restrict__ h16, const int* __restrict__ prev,
                                   float* __restrict__ out, int Ndst) {
    int t = blockIdx.x * blockDim.x + threadIdx.x;
    int r = t >> 6, lane = t & 63;
    if (r >= Ndst) return;
    uint_t g = *(const uint_t*)(h16 + (size_t)prev[r] * N_OUTC + 2 * lane);
    ((float2*)out)[(size_t)r * 128 + lane] = make_float2(bf_lo(g), bf_hi(g));
}

__global__ void spmm_atomic_kernel(const ushort_t* __restrict__ h16, const int* __restrict__ rows,
                                   const int* __restrict__ cols, const float* __restrict__ vals,
                                   int E, float* __restrict__ out) {
    long long t = (long long)blockIdx.x * blockDim.x + threadIdx.x;
    int e = (int)(t >> 6), lane = (int)(t & 63);
    if (e >= E) return;
    uint_t g = *(const uint_t*)(h16 + (size_t)cols[e] * N_OUTC + 2 * lane);
    float v = vals[e];
    int r = rows[e];
    atomicAdd(&out[(size_t)r * 256 + 128 + 2 * lane],     v * bf_lo(g));
    atomicAdd(&out[(size_t)r * 256 + 128 + 2 * lane + 1], v * bf_hi(g));
}

extern "C" void kernel_launch(void* const* d_in, const int* in_sizes, int n_in,
                              void* d_out, int out_size, void* d_ws, size_t ws_size,
                              hipStream_t stream) {
    const float* x    = (const float*)d_in[0];
    const float* W    = (const float*)d_in[1];
    const float* b    = (const float*)d_in[2];
    const float* vals = (const float*)d_in[3];
    const int*   rows = (const int*)d_in[4];
    const int*   cols = (const int*)d_in[5];
    const int*   prev = (const int*)d_in[6];
    float* out = (float*)d_out;

    const int Nsrc = in_sizes[0] / N_IN;   // 100000
    const int E    = in_sizes[3];          // 3200000
    const int Ndst = in_sizes[6];          // 50000
    const int NSB  = (Ndst + RPS - 1) / RPS;          // 98
    const int sbCap = E / NSB + 4096;                 // ~36.7K (>= mean + 27 sigma)

    char* ws = (char*)d_ws;
    size_t off = 0;
    ushort_t* h16 = (ushort_t*)(ws + off);
    off += (size_t)Nsrc * N_OUTC * sizeof(ushort_t);               // 25.6 MB
    ushort_t* wb = (ushort_t*)(ws + off);
    off += (size_t)N_OUTC * N_IN * sizeof(ushort_t);               // 64 KB
    off = (off + 255) & ~(size_t)255;
    int* sbCount  = (int*)(ws + off);                               // memset zone: NSB + 1
    int* spillCnt = sbCount + NSB;
    size_t memsetBytes = ((size_t)NSB + 1) * sizeof(int);
    off += memsetBytes;
    off = (off + 255) & ~(size_t)255;
    int* sbBase = (int*)(ws + off);
    off += (size_t)NSB * sizeof(int);
    off = (off + 255) & ~(size_t)255;
    int* rowStart = (int*)(ws + off);
    off += (size_t)Ndst * sizeof(int);
    int* rowCnt = (int*)(ws + off);
    off += (size_t)Ndst * sizeof(int);
    off = (off + 255) & ~(size_t)255;
    int4* spill = (int4*)(ws + off);
    off += (size_t)SPILL_CAP * sizeof(int4);
    off = (off + 255) & ~(size_t)255;
    int2* sbList = (int2*)(ws + off);
    off += (size_t)NSB * sbCap * sizeof(int2);                     // ~28.8 MB
    off = (off + 255) & ~(size_t)255;
    int2* csr = (int2*)(ws + off);
    off += (size_t)E * sizeof(int2);                               // 25.6 MB

    cvtW_kernel<<<(N_OUTC * N_IN + 255) / 256, 256, 0, stream>>>(W, wb, N_OUTC * N_IN);
    gemm_h_kernel<<<Nsrc / 16, 256, 0, stream>>>(x, wb, b, h16, Nsrc);

    if (off <= ws_size && NSB <= 256) {
        hipMemsetAsync(sbCount, 0, memsetBytes, stream);
        buildA_kernel<<<(E + TILE - 1) / TILE, 256, 0, stream>>>(rows, cols, vals, E,
                                                                 sbCount, sbList, sbCap, NSB,
                                                                 spillCnt, spill);
        sbscan_kernel<<<1, 256, 0, stream>>>(sbCount, sbCap, sbBase, NSB);
        sort_kernel<<<NSB, 256, 0, stream>>>(sbCount, sbBase, sbList, sbCap,
                                             csr, rowStart, rowCnt, Ndst);
        spmm_concat_kernel<<<(Ndst + 3) / 4, 256, 0, stream>>>(h16, rowStart, rowCnt, csr,
                                                               prev, out, Ndst);
        spill_kernel<<<64, 256, 0, stream>>>(h16, spill, spillCnt, out);
    } else {
        hipMemsetAsync(out, 0, (size_t)out_size * sizeof(float), stream);
        concat_only_kernel<<<((size_t)Ndst * 64 + 255) / 256, 256, 0, stream>>>(h16, prev, out, Ndst);
        spmm_atomic_kernel<<<((size_t)E * 64 + 255) / 256, 256, 0, stream>>>(h16, rows, cols, vals, E, out);
    }
}

// Round 5
// 436.980 us; speedup vs baseline: 7.3640x; 1.1140x over previous
//
#include <hip/hip_runtime.h>
#include <hip/hip_bf16.h>

#define N_IN      256
#define N_OUTC    128
#define RPS       64       // rows per superbin
#define RPS_SHIFT 6
#define NSB_MAX   1024
#define TILE      4096     // edges per build block
#define EPT       16       // edges per thread in build
#define SPILL_CAP 8192

typedef __attribute__((ext_vector_type(8))) short bf16x8;
typedef __attribute__((ext_vector_type(4))) float f32x4;
typedef unsigned short ushort_t;
typedef unsigned int uint_t;

__device__ inline unsigned short f2bf(float f) {
    unsigned u = __float_as_uint(f);
    unsigned r = u + 0x7fffu + ((u >> 16) & 1u);
    return (unsigned short)(r >> 16);
}
__device__ inline float bf_lo(uint_t g) { return __uint_as_float(g << 16); }
__device__ inline float bf_hi(uint_t g) { return __uint_as_float(g & 0xFFFF0000u); }

// ---------------- W fp32 [128,256] -> bf16 ----------------
__global__ void cvtW_kernel(const float* __restrict__ W, ushort_t* __restrict__ wb, int n) {
    int i = blockIdx.x * blockDim.x + threadIdx.x;
    if (i < n) wb[i] = f2bf(W[i]);
}

// ---------------- fused: buildA (blocks [0,nbBuild)) + gemm (rest) ----------------
__global__ __launch_bounds__(256) void fused_build_gemm_kernel(
        // build args
        const int* __restrict__ rows, const int* __restrict__ cols,
        const float* __restrict__ vals, int E,
        int* __restrict__ sbCount, int2* __restrict__ sbList, int sbCap, int nsb,
        int* __restrict__ spillCnt, int4* __restrict__ spill, int nbBuild,
        // gemm args
        const float* __restrict__ x, const ushort_t* __restrict__ wb,
        const float* __restrict__ b, ushort_t* __restrict__ h16) {
    __shared__ int cur[NSB_MAX];
    __shared__ int gbase[NSB_MAX];
    const int tid = threadIdx.x;

    if (blockIdx.x < (uint_t)nbBuild) {
        // ---- buildA: LDS-ranked superbin binning, coalesced-run writes ----
        const int base = blockIdx.x * TILE;
        for (int i = tid; i < nsb; i += 256) cur[i] = 0;
        __syncthreads();

        int ex[EPT], evb[EPT], esb[EPT], erk[EPT];
        #pragma unroll
        for (int k = 0; k < EPT; k++) {
            int e = base + tid + k * 256;
            if (e < E) {
                int r = rows[e], c = cols[e];
                evb[k] = __float_as_int(vals[e]);
                esb[k] = r >> RPS_SHIFT;
                ex[k]  = c | ((r & (RPS - 1)) << 17);
                erk[k] = atomicAdd(&cur[esb[k]], 1);
            } else esb[k] = -1;
        }
        __syncthreads();
        for (int i = tid; i < nsb; i += 256)
            gbase[i] = cur[i] ? atomicAdd(&sbCount[i], cur[i]) : 0;
        __syncthreads();

        #pragma unroll
        for (int k = 0; k < EPT; k++) {
            if (esb[k] < 0) continue;
            int pos = gbase[esb[k]] + erk[k];
            if (pos < sbCap) {
                sbList[(size_t)esb[k] * sbCap + pos] = make_int2(ex[k], evb[k]);
            } else {
                int sp = atomicAdd(spillCnt, 1);
                if (sp < SPILL_CAP)
                    spill[sp] = make_int4((esb[k] << RPS_SHIFT) + (int)(((uint_t)ex[k]) >> 17),
                                          ex[k] & 0x1FFFF, evb[k], 0);
            }
        }
        return;
    }

    // ---- gemm: h = x @ W^T + b, bf16 out ----
    const int blk  = blockIdx.x - nbBuild;
    const int wave = tid >> 6;
    const int lane = tid & 63;
    const int quad = lane >> 4;
    const int l16  = lane & 15;
    const int m0   = blk * 16;
    const int colbase = wave * 32;

    f32x4 acc0 = {0.f, 0.f, 0.f, 0.f};
    f32x4 acc1 = {0.f, 0.f, 0.f, 0.f};

    const float* xrow = x + (size_t)(m0 + l16) * N_IN + quad * 8;   // A: m=lane&15, k=quad*8+j
    const ushort_t* w0 = wb + (size_t)(colbase + l16) * N_IN + quad * 8;
    const ushort_t* w1 = w0 + 16 * N_IN;

    #pragma unroll
    for (int kb = 0; kb < N_IN; kb += 32) {
        float4 a0 = *(const float4*)(xrow + kb);
        float4 a1 = *(const float4*)(xrow + kb + 4);
        union { bf16x8 v; __hip_bfloat162 h2[4]; } u;
        u.h2[0] = __float22bfloat162_rn(make_float2(a0.x, a0.y));
        u.h2[1] = __float22bfloat162_rn(make_float2(a0.z, a0.w));
        u.h2[2] = __float22bfloat162_rn(make_float2(a1.x, a1.y));
        u.h2[3] = __float22bfloat162_rn(make_float2(a1.z, a1.w));
        bf16x8 bf0 = *(const bf16x8*)(w0 + kb);
        bf16x8 bf1 = *(const bf16x8*)(w1 + kb);
        acc0 = __builtin_amdgcn_mfma_f32_16x16x32_bf16(u.v, bf0, acc0, 0, 0, 0);
        acc1 = __builtin_amdgcn_mfma_f32_16x16x32_bf16(u.v, bf1, acc1, 0, 0, 0);
    }

    // C/D: row = quad*4 + reg, col = lane&15
    const int c0 = colbase + l16;
    const int c1 = c0 + 16;
    const float bv0 = b[c0];
    const float bv1 = b[c1];
    ushort_t* hp = h16 + (size_t)(m0 + quad * 4) * N_OUTC;
    #pragma unroll
    for (int r = 0; r < 4; r++) {
        hp[(size_t)r * N_OUTC + c0] = f2bf(acc0[r] + bv0);
        hp[(size_t)r * N_OUTC + c1] = f2bf(acc1[r] + bv1);
    }
}

// ---------------- exclusive scan of clamped superbin totals (1 block, 1024 thr) ----------------
__global__ __launch_bounds__(1024) void sbscan_kernel(const int* __restrict__ sbCount, int sbCap,
                                                      int* __restrict__ sbBase, int nsb) {
    __shared__ int a[NSB_MAX], bsh[NSB_MAX];
    int tid = threadIdx.x;
    int v = 0;
    if (tid < nsb) { v = sbCount[tid]; if (v > sbCap) v = sbCap; }
    a[tid] = v; __syncthreads();
    int* src = a; int* dst = bsh;
    for (int off = 1; off < 1024; off <<= 1) {
        dst[tid] = src[tid] + ((tid >= off) ? src[tid - off] : 0);
        __syncthreads();
        int* t = src; src = dst; dst = t;
    }
    if (tid < nsb) sbBase[tid] = tid ? src[tid - 1] : 0;
}

// ---------------- sort: superbin list -> CSR (in-L2 counting sort, 64 rows/sb) ----------------
__global__ __launch_bounds__(256) void sort_kernel(const int* __restrict__ sbCount,
                                                   const int* __restrict__ sbBase,
                                                   const int2* __restrict__ sbList, int sbCap,
                                                   int2* __restrict__ csr,
                                                   int* __restrict__ rowStart, int* __restrict__ rowCnt,
                                                   int Ndst) {
    __shared__ int hist[RPS];
    __shared__ int scanA[RPS];
    __shared__ int curx[RPS];
    const int sb  = blockIdx.x;
    const int tid = threadIdx.x;
    int len = sbCount[sb]; if (len > sbCap) len = sbCap;
    const int base = sbBase[sb];
    const int2* lp = sbList + (size_t)sb * sbCap;

    if (tid < RPS) hist[tid] = 0;
    __syncthreads();

    // phase 1: histogram (4-deep prefetch)
    int i = tid;
    for (; i + 768 < len; i += 1024) {
        int x0 = lp[i].x, x1 = lp[i + 256].x, x2 = lp[i + 512].x, x3 = lp[i + 768].x;
        atomicAdd(&hist[((uint_t)x0) >> 17], 1);
        atomicAdd(&hist[((uint_t)x1) >> 17], 1);
        atomicAdd(&hist[((uint_t)x2) >> 17], 1);
        atomicAdd(&hist[((uint_t)x3) >> 17], 1);
    }
    for (; i < len; i += 256) atomicAdd(&hist[((uint_t)lp[i].x) >> 17], 1);
    __syncthreads();

    // phase 2: inclusive scan over 64 rows (predicated Hillis-Steele)
    if (tid < RPS) scanA[tid] = hist[tid];
    __syncthreads();
    for (int off = 1; off < RPS; off <<= 1) {
        int t = 0;
        if (tid < RPS) t = scanA[tid] + ((tid >= off) ? scanA[tid - off] : 0);
        __syncthreads();
        if (tid < RPS) scanA[tid] = t;
        __syncthreads();
    }
    if (tid < RPS) {
        int excl = tid ? scanA[tid - 1] : 0;
        curx[tid] = excl;
        int r = sb * RPS + tid;
        if (r < Ndst) { rowStart[r] = base + excl; rowCnt[r] = hist[tid]; }
    }
    __syncthreads();

    // phase 3: scatter (4-deep prefetch); writes stay within this sb's CSR span (L2-resident)
    i = tid;
    for (; i + 768 < len; i += 1024) {
        int2 e0 = lp[i], e1 = lp[i + 256], e2 = lp[i + 512], e3 = lp[i + 768];
        int p0 = atomicAdd(&curx[((uint_t)e0.x) >> 17], 1);
        int p1 = atomicAdd(&curx[((uint_t)e1.x) >> 17], 1);
        int p2 = atomicAdd(&curx[((uint_t)e2.x) >> 17], 1);
        int p3 = atomicAdd(&curx[((uint_t)e3.x) >> 17], 1);
        csr[(size_t)base + p0] = make_int2(e0.x & 0x1FFFF, e0.y);
        csr[(size_t)base + p1] = make_int2(e1.x & 0x1FFFF, e1.y);
        csr[(size_t)base + p2] = make_int2(e2.x & 0x1FFFF, e2.y);
        csr[(size_t)base + p3] = make_int2(e3.x & 0x1FFFF, e3.y);
    }
    for (; i < len; i += 256) {
        int2 e = lp[i];
        int pos = atomicAdd(&curx[((uint_t)e.x) >> 17], 1);
        csr[(size_t)base + pos] = make_int2(e.x & 0x1FFFF, e.y);
    }
}

// ---------------- SpMM: wave per dst row, coalesced edge loads + shfl broadcast ----------------
__global__ __launch_bounds__(256) void spmm_concat_kernel(const ushort_t* __restrict__ h16,
                                                          const int* __restrict__ rowStart,
                                                          const int* __restrict__ rowCnt,
                                                          const int2* __restrict__ csr,
                                                          const int* __restrict__ prev,
                                                          float* __restrict__ out, int Ndst) {
    int r = blockIdx.x * 4 + (threadIdx.x >> 6);
    if (r >= Ndst) return;
    const int lane = threadIdx.x & 63;
    const int cnt = rowCnt[r];
    const int2* bk = csr + rowStart[r];

    float2 acc = {0.f, 0.f};
    for (int bse = 0; bse < cnt; bse += 64) {
        int idx = bse + lane;
        int2 my = make_int2(0, 0);             // pad: v=0 -> zero contribution, c=0 safe
        if (idx < cnt) my = bk[idx];
        int m = cnt - bse; if (m > 64) m = 64;
        int mg = (m + 7) & ~7;
        for (int j = 0; j < mg; j += 8) {
            int c0 = __shfl(my.x, j + 0), c1 = __shfl(my.x, j + 1);
            int c2 = __shfl(my.x, j + 2), c3 = __shfl(my.x, j + 3);
            int c4 = __shfl(my.x, j + 4), c5 = __shfl(my.x, j + 5);
            int c6 = __shfl(my.x, j + 6), c7 = __shfl(my.x, j + 7);
            uint_t g0 = *(const uint_t*)(h16 + (size_t)c0 * N_OUTC + 2 * lane);
            uint_t g1 = *(const uint_t*)(h16 + (size_t)c1 * N_OUTC + 2 * lane);
            uint_t g2 = *(const uint_t*)(h16 + (size_t)c2 * N_OUTC + 2 * lane);
            uint_t g3 = *(const uint_t*)(h16 + (size_t)c3 * N_OUTC + 2 * lane);
            uint_t g4 = *(const uint_t*)(h16 + (size_t)c4 * N_OUTC + 2 * lane);
            uint_t g5 = *(const uint_t*)(h16 + (size_t)c5 * N_OUTC + 2 * lane);
            uint_t g6 = *(const uint_t*)(h16 + (size_t)c6 * N_OUTC + 2 * lane);
            uint_t g7 = *(const uint_t*)(h16 + (size_t)c7 * N_OUTC + 2 * lane);
            float v0 = __int_as_float(__shfl(my.y, j + 0));
            float v1 = __int_as_float(__shfl(my.y, j + 1));
            float v2 = __int_as_float(__shfl(my.y, j + 2));
            float v3 = __int_as_float(__shfl(my.y, j + 3));
            float v4 = __int_as_float(__shfl(my.y, j + 4));
            float v5 = __int_as_float(__shfl(my.y, j + 5));
            float v6 = __int_as_float(__shfl(my.y, j + 6));
            float v7 = __int_as_float(__shfl(my.y, j + 7));
            acc.x += v0 * bf_lo(g0); acc.y += v0 * bf_hi(g0);
            acc.x += v1 * bf_lo(g1); acc.y += v1 * bf_hi(g1);
            acc.x += v2 * bf_lo(g2); acc.y += v2 * bf_hi(g2);
            acc.x += v3 * bf_lo(g3); acc.y += v3 * bf_hi(g3);
            acc.x += v4 * bf_lo(g4); acc.y += v4 * bf_hi(g4);
            acc.x += v5 * bf_lo(g5); acc.y += v5 * bf_hi(g5);
            acc.x += v6 * bf_lo(g6); acc.y += v6 * bf_hi(g6);
            acc.x += v7 * bf_lo(g7); acc.y += v7 * bf_hi(g7);
        }
    }

    int p = prev[r];
    uint_t g = *(const uint_t*)(h16 + (size_t)p * N_OUTC + 2 * lane);
    float2* o = (float2*)(out + (size_t)r * 256);
    o[lane]      = make_float2(bf_lo(g), bf_hi(g));
    o[64 + lane] = make_float2(acc.x, acc.y);
}

// ---------------- spill fixup (expected empty) ----------------
__global__ void spill_kernel(const ushort_t* __restrict__ h16, const int4* __restrict__ spill,
                             const int* __restrict__ spillCnt, float* __restrict__ out) {
    int n = *spillCnt; if (n > SPILL_CAP) n = SPILL_CAP;
    int total = n * 64;
    for (int t = blockIdx.x * blockDim.x + threadIdx.x; t < total; t += gridDim.x * blockDim.x) {
        int idx = t >> 6, lane = t & 63;
        int4 s = spill[idx];
        uint_t g = *(const uint_t*)(h16 + (size_t)s.y * N_OUTC + 2 * lane);
        float v = __int_as_float(s.z);
        atomicAdd(&out[(size_t)s.x * 256 + 128 + 2 * lane],     v * bf_lo(g));
        atomicAdd(&out[(size_t)s.x * 256 + 128 + 2 * lane + 1], v * bf_hi(g));
    }
}

// ---------------- fallback path (ws too small; not expected) ----------------
__global__ __launch_bounds__(256) void gemm_only_kernel(const float* __restrict__ x,
                                                        const ushort_t* __restrict__ wb,
                                                        const float* __restrict__ b,
                                                        ushort_t* __restrict__ h16) {
    const int tid  = threadIdx.x;
    const int wave = tid >> 6;
    const int lane = tid & 63;
    const int quad = lane >> 4;
    const int l16  = lane & 15;
    const int m0   = blockIdx.x * 16;
    const int colbase = wave * 32;
    f32x4 acc0 = {0.f, 0.f, 0.f, 0.f};
    f32x4 acc1 = {0.f, 0.f, 0.f, 0.f};
    const float* xrow = x + (size_t)(m0 + l16) * N_IN + quad * 8;
    const ushort_t* w0 = wb + (size_t)(colbase + l16) * N_IN + quad * 8;
    const ushort_t* w1 = w0 + 16 * N_IN;
    #pragma unroll
    for (int kb = 0; kb < N_IN; kb += 32) {
        float4 a0 = *(const float4*)(xrow + kb);
        float4 a1 = *(const float4*)(xrow + kb + 4);
        union { bf16x8 v; __hip_bfloat162 h2[4]; } u;
        u.h2[0] = __float22bfloat162_rn(make_float2(a0.x, a0.y));
        u.h2[1] = __float22bfloat162_rn(make_float2(a0.z, a0.w));
        u.h2[2] = __float22bfloat162_rn(make_float2(a1.x, a1.y));
        u.h2[3] = __float22bfloat162_rn(make_float2(a1.z, a1.w));
        bf16x8 bf0 = *(const bf16x8*)(w0 + kb);
        bf16x8 bf1 = *(const bf16x8*)(w1 + kb);
        acc0 = __builtin_amdgcn_mfma_f32_16x16x32_bf16(u.v, bf0, acc0, 0, 0, 0);
        acc1 = __builtin_amdgcn_mfma_f32_16x16x32_bf16(u.v, bf1, acc1, 0, 0, 0);
    }
    const int c0 = colbase + l16;
    const int c1 = c0 + 16;
    const float bv0 = b[c0];
    const float bv1 = b[c1];
    ushort_t* hp = h16 + (size_t)(m0 + quad * 4) * N_OUTC;
    #pragma unroll
    for (int r = 0; r < 4; r++) {
        hp[(size_t)r * N_OUTC + c0] = f2bf(acc0[r] + bv0);
        hp[(size_t)r * N_OUTC + c1] = f2bf(acc1[r] + bv1);
    }
}

__global__ void concat_only_kernel(const ushort_t* __restrict__ h16, const int* __restrict__ prev,
                                   float* __restrict__ out, int Ndst) {
    int t = blockIdx.x * blockDim.x + threadIdx.x;
    int r = t >> 6, lane = t & 63;
    if (r >= Ndst) return;
    uint_t g = *(const uint_t*)(h16 + (size_t)prev[r] * N_OUTC + 2 * lane);
    ((float2*)out)[(size_t)r * 128 + lane] = make_float2(bf_lo(g), bf_hi(g));
}

__global__ void spmm_atomic_kernel(const ushort_t* __restrict__ h16, const int* __restrict__ rows,
                                   const int* __restrict__ cols, const float* __restrict__ vals,
                                   int E, float* __restrict__ out) {
    long long t = (long long)blockIdx.x * blockDim.x + threadIdx.x;
    int e = (int)(t >> 6), lane = (int)(t & 63);
    if (e >= E) return;
    uint_t g = *(const uint_t*)(h16 + (size_t)cols[e] * N_OUTC + 2 * lane);
    float v = vals[e];
    int r = rows[e];
    atomicAdd(&out[(size_t)r * 256 + 128 + 2 * lane],     v * bf_lo(g));
    atomicAdd(&out[(size_t)r * 256 + 128 + 2 * lane + 1], v * bf_hi(g));
}

extern "C" void kernel_launch(void* const* d_in, const int* in_sizes, int n_in,
                              void* d_out, int out_size, void* d_ws, size_t ws_size,
                              hipStream_t stream) {
    const float* x    = (const float*)d_in[0];
    const float* W    = (const float*)d_in[1];
    const float* b    = (const float*)d_in[2];
    const float* vals = (const float*)d_in[3];
    const int*   rows = (const int*)d_in[4];
    const int*   cols = (const int*)d_in[5];
    const int*   prev = (const int*)d_in[6];
    float* out = (float*)d_out;

    const int Nsrc = in_sizes[0] / N_IN;   // 100000
    const int E    = in_sizes[3];          // 3200000
    const int Ndst = in_sizes[6];          // 50000
    const int NSB  = (Ndst + RPS - 1) / RPS;           // 782
    const int sbCap = E / NSB + 516;                   // mean ~4092 + 8 sigma
    const int nbBuild = (E + TILE - 1) / TILE;         // 782
    const int gemmBlocks = Nsrc / 16;                  // 6250

    char* ws = (char*)d_ws;
    size_t off = 0;
    ushort_t* h16 = (ushort_t*)(ws + off);
    off += (size_t)Nsrc * N_OUTC * sizeof(ushort_t);               // 25.6 MB
    ushort_t* wb = (ushort_t*)(ws + off);
    off += (size_t)N_OUTC * N_IN * sizeof(ushort_t);               // 64 KB
    off = (off + 255) & ~(size_t)255;
    int* sbCount  = (int*)(ws + off);                               // memset zone: NSB + 1
    int* spillCnt = sbCount + NSB;
    size_t memsetBytes = ((size_t)NSB + 1) * sizeof(int);
    off += memsetBytes;
    off = (off + 255) & ~(size_t)255;
    int* sbBase = (int*)(ws + off);
    off += (size_t)NSB * sizeof(int);
    off = (off + 255) & ~(size_t)255;
    int* rowStart = (int*)(ws + off);
    off += (size_t)Ndst * sizeof(int);
    int* rowCnt = (int*)(ws + off);
    off += (size_t)Ndst * sizeof(int);
    off = (off + 255) & ~(size_t)255;
    int4* spill = (int4*)(ws + off);
    off += (size_t)SPILL_CAP * sizeof(int4);
    off = (off + 255) & ~(size_t)255;
    int2* sbList = (int2*)(ws + off);
    off += (size_t)NSB * sbCap * sizeof(int2);                     // ~28.8 MB
    off = (off + 255) & ~(size_t)255;
    int2* csr = (int2*)(ws + off);
    off += (size_t)E * sizeof(int2);                               // 25.6 MB

    cvtW_kernel<<<(N_OUTC * N_IN + 255) / 256, 256, 0, stream>>>(W, wb, N_OUTC * N_IN);

    if (off <= ws_size && NSB <= NSB_MAX) {
        hipMemsetAsync(sbCount, 0, memsetBytes, stream);
        fused_build_gemm_kernel<<<nbBuild + gemmBlocks, 256, 0, stream>>>(
            rows, cols, vals, E, sbCount, sbList, sbCap, NSB, spillCnt, spill, nbBuild,
            x, wb, b, h16);
        sbscan_kernel<<<1, 1024, 0, stream>>>(sbCount, sbCap, sbBase, NSB);
        sort_kernel<<<NSB, 256, 0, stream>>>(sbCount, sbBase, sbList, sbCap,
                                             csr, rowStart, rowCnt, Ndst);
        spmm_concat_kernel<<<(Ndst + 3) / 4, 256, 0, stream>>>(h16, rowStart, rowCnt, csr,
                                                               prev, out, Ndst);
        spill_kernel<<<64, 256, 0, stream>>>(h16, spill, spillCnt, out);
    } else {
        gemm_only_kernel<<<gemmBlocks, 256, 0, stream>>>(x, wb, b, h16);
        hipMemsetAsync(out, 0, (size_t)out_size * sizeof(float), stream);
        concat_only_kernel<<<((size_t)Ndst * 64 + 255) / 256, 256, 0, stream>>>(h16, prev, out, Ndst);
        spmm_atomic_kernel<<<((size_t)E * 64 + 255) / 256, 256, 0, stream>>>(h16, rows, cols, vals, E, out);
    }
}